// Round 7
// baseline (739.593 us; speedup 1.0000x reference)
//
#include <hip/hip_runtime.h>
#include <math.h>

#define Bn 16
#define Ln 2500
#define En 100
#define FM 50
#define Yn 8921
#define KS 10
#define LP 2501
#define NT 40              // 40 tiles of 64 l (2560 >= 2501)
#define TILE_BYTES 19456   // hA 10240 + hT 9216
#define TILE_SHORTS 9728
#define HT_OFF 5120        // shorts
#define CH_FULL 19         // 1KB chunks per full tile
#define CH_A 10            // chunks covering hA only
#define NW 8               // waves per K2 block
#define YB 128             // y per K2 block
#define NYB 70             // ceil(8921/128)
#define AWS 68             // aw row stride (floats); 68 breaks 256B row-alias

typedef __attribute__((ext_vector_type(8))) short short8;
typedef __attribute__((ext_vector_type(4))) float f32x4;
typedef __attribute__((ext_vector_type(2))) float f32x2;

union S8 { short8 v; long l2[2]; short s[8]; };

__device__ __forceinline__ short f2bf(float f){
  unsigned u = __float_as_uint(f);
  unsigned r = (u + 0x7fffu + ((u >> 16) & 1u)) >> 16;
  return (short)r;
}

// async 16B/lane global->LDS
__device__ __forceinline__ void g2l16(const void* g, void* l){
  __builtin_amdgcn_global_load_lds(
      (const __attribute__((address_space(1))) unsigned int*)g,
      (__attribute__((address_space(3))) unsigned int*)l, 16, 0, 0);
}

__device__ __forceinline__ void stage_chunks(const char* __restrict__ gbase,
                                             char* lbase, int wave, int lane,
                                             int nch, int nw){
  for (int chunk = wave; chunk < nch; chunk += nw)
    g2l16(gbase + chunk * 1024 + lane * 16, lbase + chunk * 1024 + lane * 16);
}

// uniform 3 loads per wave (slots >= 19 duplicate chunk 18: same data, benign)
__device__ __forceinline__ void stage3(const char* __restrict__ gbase,
                                       char* lbase, int wave, int lane){
#pragma unroll
  for (int k = 0; k < 3; k++){
    int slot = wave + 8 * k;
    int ch = slot < CH_FULL ? slot : CH_FULL - 1;
    g2l16(gbase + ch * 1024 + lane * 16, lbase + ch * 1024 + lane * 16);
  }
}

// ---------------- K0: transpose conv_w (Fm,E,K) -> WT[e*10+k][f(64 pad0)] --------------
__global__ void k0_wt(const float* __restrict__ cw, float* __restrict__ WT){
  int i = blockIdx.x * 256 + threadIdx.x;
  if (i < 64000){
    int f = i & 63, ek = i >> 6;
    WT[i] = (f < FM) ? cw[f * 1000 + ek] : 0.f;
  }
}

// ---------------- K1: conv+bias+tanh -> per-tile blob [hA pad | hT pad] bf16 -----------
__global__ __launch_bounds__(256) void k1_conv(
    const float* __restrict__ x, const float* __restrict__ WT,
    const float* __restrict__ conv_b, short* __restrict__ Hp)
{
  int t = blockIdx.x, b = blockIdx.y, tid = threadIdx.x;
  __shared__ float x_s[100 * 76];       // [e][row(73) pad 76]
  __shared__ short h_t[64 * 69];        // [l][f pad 69]

  int r0 = 64 * t - 5;
  for (int d = tid; d < 7300; d += 256){
    int row = d / 100, e = d - row * 100;
    int gr = r0 + row;
    float v = (gr >= 0 && gr < Ln) ? x[((size_t)b * Ln + gr) * 100 + e] : 0.f;
    x_s[e * 76 + row] = v;
  }
  __syncthreads();

  int f = tid & 63, lsub = tid >> 6;
  float acc[16];
#pragma unroll
  for (int j = 0; j < 16; j++) acc[j] = 0.f;

  for (int e = 0; e < 100; e++){
    float xv[25];
    const float* xr = x_s + e * 76 + lsub * 16;
#pragma unroll
    for (int i = 0; i < 6; i++){
      f32x4 q = *(const f32x4*)(xr + 4 * i);
      xv[4*i+0] = q[0]; xv[4*i+1] = q[1]; xv[4*i+2] = q[2]; xv[4*i+3] = q[3];
    }
    xv[24] = xr[24];
#pragma unroll
    for (int k = 0; k < KS; k++){
      float wv = WT[(e * 10 + k) * 64 + f];
#pragma unroll
      for (int j = 0; j < 16; j++) acc[j] += wv * xv[j + k];
    }
  }

  float bias = (f < FM) ? conv_b[f] : 0.f;
  size_t tbS = (size_t)(b * NT + t) * TILE_SHORTS;
#pragma unroll
  for (int j = 0; j < 16; j++){
    int l = lsub * 16 + j;
    int lgl = 64 * t + l;
    float hv = (lgl < LP && f < FM) ? tanhf(acc[j] + bias) : 0.f;
    short hb = f2bf(hv);
    // hA image: [fgrp(4)][l(64)][20]  (cols 16..19 are unread holes)
    Hp[tbS + (size_t)(f >> 4) * 1280 + (size_t)l * 20 + (f & 15)] = hb;
    h_t[l * 69 + f] = hb;
  }
  __syncthreads();
  int lane = tid & 63, wave = tid >> 6;
#pragma unroll
  for (int i = 0; i < 16; i++){
    int fo = wave + 4 * i;
    // hT image: [f(64)][72]  (cols 64..71 unread holes)
    Hp[tbS + HT_OFF + (size_t)fo * 72 + lane] = h_t[lane * 69 + fo];
  }
}

// ---------------- shared fragment helpers ----------------
__device__ __forceinline__ void scores_tile(const short* __restrict__ h_s,
                                            const S8 bu[2], int c, int g, f32x4 d[4])
{
#pragma unroll
  for (int ms = 0; ms < 4; ms++){
    f32x4 acc = {0.f, 0.f, 0.f, 0.f};
#pragma unroll
    for (int kf = 0; kf < 2; kf++){
      const short* pa = h_s + (2 * kf) * 1280 + (c + 16 * ms) * 20 + 4 * g;
      S8 a;
      a.l2[0] = *(const long*)pa;
      a.l2[1] = *(const long*)(pa + 1280);
      acc = __builtin_amdgcn_mfma_f32_16x16x32_bf16(a.v, bu[kf].v, acc, 0, 0, 0);
    }
    d[ms] = acc;
  }
}

__device__ __forceinline__ void load_bu(const float* __restrict__ U_w,
                                        int ywave, int c, int g, S8 bu[2]){
  int yv = ywave + c;
#pragma unroll
  for (int kf = 0; kf < 2; kf++)
#pragma unroll
    for (int i = 0; i < 8; i++){
      int fidx = 4 * g + (i & 3) + 16 * (i >> 2) + 32 * kf;
      float v = (yv < Yn && fidx < FM) ? U_w[yv * FM + fidx] : 0.f;
      bu[kf].s[i] = f2bf(v);
    }
}

// ---------------- K2a: S = sum_l exp(score) -> invS  (R5 proven form) ----------------
__global__ __launch_bounds__(512, 4) void k2a_sum(
    const short* __restrict__ Hp, const float* __restrict__ U_w,
    float* __restrict__ invS_out)
{
  int id = blockIdx.x;
  int xcd = id & 7, rr = id >> 3;           // rr in [0,140)
  int b   = xcd + ((rr >= NYB) ? 8 : 0);
  int y0  = ((rr >= NYB) ? rr - NYB : rr) * YB;

  int tid = threadIdx.x;
  int lane = tid & 63, wave = tid >> 6;
  int c = lane & 15, g = lane >> 4;
  int ywave = y0 + wave * 16;

  __shared__ __align__(16) short buf[2][5120];   // hA only

  S8 bu[2];
  load_bu(U_w, ywave, c, g, bu);

  const char* blob = (const char*)Hp + (size_t)b * NT * TILE_BYTES;

  float S = 0.f;
  int cur = 0;
  stage_chunks(blob, (char*)buf[0], wave, lane, CH_A, NW);
  for (int t = 0; t < NT; t++){
    __syncthreads();
    if (t + 1 < NT)
      stage_chunks(blob + (size_t)(t + 1) * TILE_BYTES, (char*)buf[cur ^ 1], wave, lane, CH_A, NW);
    f32x4 d[4];
    scores_tile(buf[cur], bu, c, g, d);
    if (t < NT - 1){
#pragma unroll
      for (int ms = 0; ms < 4; ms++)
#pragma unroll
        for (int q = 0; q < 4; q++) S += __expf(d[ms][q]);
    } else {
#pragma unroll
      for (int ms = 0; ms < 4; ms++)
#pragma unroll
        for (int q = 0; q < 4; q++){
          int l = 64 * t + 16 * ms + 4 * g + q;
          if (l < LP) S += __expf(d[ms][q]);
        }
    }
    cur ^= 1;
  }
  S += __shfl_xor(S, 16);
  S += __shfl_xor(S, 32);
  if (lane < 16){
    int yv = ywave + lane;
    if (yv < Yn) invS_out[b * Yn + yv] = 1.f / S;
  }
}

// ---------------- K2b: alpha (wide pipelined full-line writes) + m + logits ------------
__global__ __launch_bounds__(512, 4) void k2b_alpha(
    const short* __restrict__ Hp,
    const float* __restrict__ U_w, const float* __restrict__ final_w,
    const float* __restrict__ final_b, const float* __restrict__ invS_arr,
    float* __restrict__ logits, float* __restrict__ alpha_out,
    float* __restrict__ dump)
{
  int id = blockIdx.x;
  int xcd = id & 7, rr = id >> 3;           // rr in [0,140)
  int b   = xcd + ((rr >= NYB) ? 8 : 0);
  int y0  = ((rr >= NYB) ? rr - NYB : rr) * YB;

  int tid = threadIdx.x;
  int lane = tid & 63, wave = tid >> 6;     // wave 0..7
  int c = lane & 15, g = lane >> 4;
  int ywave = y0 + wave * 16;

  __shared__ __align__(16) short buf[2][TILE_SHORTS];
  __shared__ float awf[NW * 16 * AWS];      // per-wave [16 rows][68]

  S8 bu[2];
  load_bu(U_w, ywave, c, g, bu);

  float invS = 0.f;
  { int yv = ywave + c; if (yv < Yn) invS = invS_arr[b * Yn + yv]; }

  // alpha row phase: float index of (y,0) is 142737 + (b*8921+y)*2501 ; mod 32:
  int Kf = (17 + 29 * b + 5 * ywave) & 31;
  int fc = (Kf + 5 * c) & 31;

  f32x4 m2[4];
#pragma unroll
  for (int fs = 0; fs < 4; fs++) m2[fs] = (f32x4){0.f, 0.f, 0.f, 0.f};

  const char* blob = (const char*)Hp + (size_t)b * NT * TILE_BYTES;
  float* aw = awf + wave * (16 * AWS);
  float* dumpf = dump + (size_t)id * 128;

  int cur = 0;
  stage3(blob, (char*)buf[0], wave, lane);
  for (int t = 0; t < NT; t++){
    // vmcnt ledger (per wave, issue order L then S): t=1 top: [L(1)=3, S(0)=16]
    // -> vmcnt(16) retires L(1). t>=2 top: [S(t-2)<=16, L(t)=3, S(t-1)=8]
    // -> vmcnt(8) retires S(t-2)+L(t), leaves S(t-1).
    if (t == 0)      asm volatile("s_waitcnt vmcnt(0) lgkmcnt(0)" ::: "memory");
    else if (t == 1) asm volatile("s_waitcnt vmcnt(16) lgkmcnt(0)" ::: "memory");
    else             asm volatile("s_waitcnt vmcnt(8) lgkmcnt(0)" ::: "memory");
    __builtin_amdgcn_s_barrier();
    if (t + 1 < NT)
      stage3(blob + (size_t)(t + 1) * TILE_BYTES, (char*)buf[cur ^ 1], wave, lane);
    __builtin_amdgcn_sched_barrier(0);      // pin: loads issued before everything below

    const short* h_s  = buf[cur];
    const short* ht_s = buf[cur] + HT_OFF;
    f32x4 d[4];
    scores_tile(h_s, bu, c, g, d);
    float a[16];
    if (t < NT - 1){
#pragma unroll
      for (int ms = 0; ms < 4; ms++)
#pragma unroll
        for (int q = 0; q < 4; q++) a[ms * 4 + q] = __expf(d[ms][q]) * invS;
    } else {
#pragma unroll
      for (int ms = 0; ms < 4; ms++)
#pragma unroll
        for (int q = 0; q < 4; q++){
          int l = 64 * t + 16 * ms + 4 * g + q;
          a[ms * 4 + q] = (l < LP) ? __expf(d[ms][q]) * invS : 0.f;
        }
    }

    // GEMM2: m += alpha * h   (A2 repacked in-lane, R5 proven f2bf form)
#pragma unroll
    for (int kl = 0; kl < 2; kl++){
      S8 a2;
#pragma unroll
      for (int i = 0; i < 8; i++)
        a2.s[i] = f2bf(a[(2 * kl + (i >> 2)) * 4 + (i & 3)]);
#pragma unroll
      for (int fs = 0; fs < 4; fs++){
        const short* pb = ht_s + (16 * fs + c) * 72 + 4 * g + 32 * kl;
        S8 b2;
        b2.l2[0] = *(const long*)pb;
        b2.l2[1] = *(const long*)(pb + 16);
        m2[fs] = __builtin_amdgcn_mfma_f32_16x16x32_bf16(a2.v, b2.v, m2[fs], 0, 0, 0);
      }
    }

    // alpha out: two half-rounds of 32 cols; full aligned 128B lines
#pragma unroll
    for (int hs = 0; hs < 2; hs++){
      // scatter 32 new alphas at row phase fc -> positions [fc, fc+32) (<=63)
#pragma unroll
      for (int mh = 0; mh < 2; mh++)
#pragma unroll
        for (int q = 0; q < 4; q++)
          aw[c * AWS + fc + 16 * mh + 4 * g + q] = a[(2 * hs + mh) * 4 + q];
      if (t >= 1 && t <= 38){
        // wide path: 4 dwordx2 stores/wave; all cols in [33,2496] -> only y mask
        // (8B alignment proven: global float idx === k2 (mod 32), k2 even)
#pragma unroll
        for (int i = 0; i < 4; i++){
          int jj = 4 * i + (lane >> 4);
          int k2 = (lane & 15) * 2;
          int fj = (Kf + 5 * jj) & 31;
          int gcol = 64 * t + 32 * hs - fj + k2;
          f32x2 v2 = *(const f32x2*)(aw + jj * AWS + k2);
          int yj = ywave + jj;
          bool ok = (yj < Yn);
          f32x2* dst = ok ? (f32x2*)(alpha_out + (size_t)(b * Yn + yj) * LP + gcol)
                          : (f32x2*)(dumpf + 2 * lane);
          __builtin_nontemporal_store(v2, dst);
        }
      } else {
        // boundary path: 8 masked dword stores/wave
#pragma unroll
        for (int i = 0; i < 8; i++){
          int jj  = 2 * i + (lane >> 5);
          int k32 = lane & 31;
          int fj  = (Kf + 5 * jj) & 31;
          int gcol = 64 * t + 32 * hs - fj + k32;
          float v = aw[jj * AWS + k32];
          int yj = ywave + jj;
          bool ok = (gcol >= 0) & (gcol < LP) & (yj < Yn);
          float* dst = ok ? (alpha_out + (size_t)(b * Yn + yj) * LP + gcol)
                          : (dumpf + lane);
          __builtin_nontemporal_store(v, dst);
        }
      }
      // shift carry [32, 32+fj) -> [0, fj)
#pragma unroll
      for (int i = 0; i < 8; i++){
        int jj  = 2 * i + (lane >> 5);
        int k32 = lane & 31;
        int fj  = (Kf + 5 * jj) & 31;
        if (k32 < fj) aw[jj * AWS + k32] = aw[jj * AWS + 32 + k32];
      }
    }
    cur ^= 1;
  }

  // ---- epilogue: logits ----
  float part[4];
#pragma unroll
  for (int q = 0; q < 4; q++){
    int yy = ywave + 4 * g + q;
    float p = 0.f;
    if (yy < Yn){
#pragma unroll
      for (int fs = 0; fs < 4; fs++){
        int fcol = fs * 16 + c;
        if (fcol < FM) p += m2[fs][q] * final_w[yy * FM + fcol];
      }
    }
#pragma unroll
    for (int off = 1; off <= 8; off <<= 1) p += __shfl_xor(p, off);
    part[q] = p;
  }
  if (c == 0){
#pragma unroll
    for (int q = 0; q < 4; q++){
      int yy = ywave + 4 * g + q;
      if (yy < Yn) logits[(size_t)b * Yn + yy] = part[q] + final_b[yy];
    }
  }
}

// ---------------- K3: log_softmax over Y + BCE loss partials ----------------
__global__ __launch_bounds__(256) void k3_lsm(
    const float* __restrict__ logits, const float* __restrict__ target,
    float* __restrict__ proba, float* __restrict__ lossp)
{
  int b = blockIdx.x, tid = threadIdx.x;
  int lane = tid & 63, wave = tid >> 6;
  __shared__ float red[4];
  const float* lg = logits + (size_t)b * Yn;
  const float* tg = target + (size_t)b * Yn;

  float m = -INFINITY;
  for (int y = tid; y < Yn; y += 256) m = fmaxf(m, lg[y]);
#pragma unroll
  for (int off = 1; off <= 32; off <<= 1) m = fmaxf(m, __shfl_xor(m, off));
  if (lane == 0) red[wave] = m;
  __syncthreads();
  m = fmaxf(fmaxf(red[0], red[1]), fmaxf(red[2], red[3]));
  __syncthreads();

  float s = 0.f;
  for (int y = tid; y < Yn; y += 256) s += __expf(lg[y] - m);
#pragma unroll
  for (int off = 1; off <= 32; off <<= 1) s += __shfl_xor(s, off);
  if (lane == 0) red[wave] = s;
  __syncthreads();
  s = red[0] + red[1] + red[2] + red[3];
  __syncthreads();
  float lse = m + logf(s);

  float ls = 0.f;
  for (int y = tid; y < Yn; y += 256){
    float xx = lg[y];
    proba[(size_t)b * Yn + y] = xx - lse;
    ls += fmaxf(xx, 0.f) - xx * tg[y] + log1pf(__expf(-fabsf(xx)));
  }
#pragma unroll
  for (int off = 1; off <= 32; off <<= 1) ls += __shfl_xor(ls, off);
  if (lane == 0) red[wave] = ls;
  __syncthreads();
  if (tid == 0) lossp[b] = red[0] + red[1] + red[2] + red[3];
}

__global__ void k4_loss(const float* __restrict__ lossp, float* __restrict__ out){
  if (threadIdx.x == 0){
    float s = 0.f;
    for (int i = 0; i < Bn; i++) s += lossp[i];
    out[142736] = s / 142736.f;
  }
}

// ---------------- launch ----------------
extern "C" void kernel_launch(void* const* d_in, const int* in_sizes, int n_in,
                              void* d_out, int out_size, void* d_ws, size_t ws_size,
                              hipStream_t stream)
{
  const float* x       = (const float*)d_in[0];
  const float* target  = (const float*)d_in[1];
  const float* conv_w  = (const float*)d_in[2];
  const float* conv_b  = (const float*)d_in[3];
  const float* U_w     = (const float*)d_in[4];
  const float* final_w = (const float*)d_in[5];
  const float* final_b = (const float*)d_in[6];
  float* out = (float*)d_out;

  char* ws = (char*)d_ws;
  short* Hp     = (short*)(ws);                 // 16*40*19456 = 12,451,840 B
  float* WT     = (float*)(ws + 12451840);      //   256,000 B
  float* logits = (float*)(ws + 12707840);      //   570,944 B
  float* lossp  = (float*)(ws + 13278784);      //        64 B
  float* invS   = (float*)(ws + 13278848);      //   570,944 B
  float* dump   = (float*)(ws + 13849792);      //   573,440 B  (1120 blocks * 512B)

  float* proba     = out;              // B*Y
  float* alpha_out = out + 142737;     // after proba + loss

  k0_wt<<<dim3(250), dim3(256), 0, stream>>>(conv_w, WT);
  k1_conv<<<dim3(NT, Bn), dim3(256), 0, stream>>>(x, WT, conv_b, Hp);
  k2a_sum<<<dim3(8 * 2 * NYB), dim3(512), 0, stream>>>(Hp, U_w, invS);
  k2b_alpha<<<dim3(8 * 2 * NYB), dim3(512), 0, stream>>>(Hp, U_w, final_w, final_b,
                                                         invS, logits, alpha_out, dump);
  k3_lsm<<<dim3(Bn), dim3(256), 0, stream>>>(logits, target, proba, lossp);
  k4_loss<<<dim3(1), dim3(64), 0, stream>>>(lossp, out);
}

// Round 8
// 600.841 us; speedup vs baseline: 1.2309x; 1.2309x over previous
//
#include <hip/hip_runtime.h>
#include <math.h>

#define Bn 16
#define Ln 2500
#define En 100
#define FM 50
#define Yn 8921
#define KS 10
#define LP 2501
#define NT 40              // 40 tiles of 64 l (2560 >= 2501)
#define TILE_BYTES 19456   // hA 10240 + hT 9216
#define TILE_SHORTS 9728
#define HT_OFF 5120        // shorts
#define CH_FULL 19         // 1KB chunks per full tile
#define CH_A 10            // chunks covering hA only
#define NW 8               // waves per K2 block
#define YB 128             // y per K2 block
#define NYB 70             // ceil(8921/128)

typedef __attribute__((ext_vector_type(8))) short short8;
typedef __attribute__((ext_vector_type(4))) float f32x4;

union S8 { short8 v; long l2[2]; short s[8]; };

__device__ __forceinline__ short f2bf(float f){
  unsigned u = __float_as_uint(f);
  unsigned r = (u + 0x7fffu + ((u >> 16) & 1u)) >> 16;
  return (short)r;
}

// async 16B/lane global->LDS
__device__ __forceinline__ void g2l16(const void* g, void* l){
  __builtin_amdgcn_global_load_lds(
      (const __attribute__((address_space(1))) unsigned int*)g,
      (__attribute__((address_space(3))) unsigned int*)l, 16, 0, 0);
}

__device__ __forceinline__ void stage_chunks(const char* __restrict__ gbase,
                                             char* lbase, int wave, int lane,
                                             int nch, int nw){
  for (int chunk = wave; chunk < nch; chunk += nw)
    g2l16(gbase + chunk * 1024 + lane * 16, lbase + chunk * 1024 + lane * 16);
}

// ---------------- K0: transpose conv_w (Fm,E,K) -> WT[e*10+k][f(64 pad0)] --------------
__global__ void k0_wt(const float* __restrict__ cw, float* __restrict__ WT){
  int i = blockIdx.x * 256 + threadIdx.x;
  if (i < 64000){
    int f = i & 63, ek = i >> 6;
    WT[i] = (f < FM) ? cw[f * 1000 + ek] : 0.f;
  }
}

// ---------------- K1: conv+bias+tanh -> per-tile blob [hA pad | hT pad] bf16 -----------
// 1D XCD-affine grid: tiles of batch b land on XCD b&7 (same as K2's reader mapping)
__global__ __launch_bounds__(256) void k1_conv(
    const float* __restrict__ x, const float* __restrict__ WT,
    const float* __restrict__ conv_b, short* __restrict__ Hp)
{
  int id = blockIdx.x;
  int xcd = id & 7, rr = id >> 3;           // rr in [0,80)
  int b   = xcd + ((rr >= NT) ? 8 : 0);
  int t   = (rr >= NT) ? rr - NT : rr;
  int tid = threadIdx.x;
  __shared__ float x_s[100 * 76];       // [e][row(73) pad 76]
  __shared__ short h_t[64 * 69];        // [l][f pad 69]

  int r0 = 64 * t - 5;
  for (int d = tid; d < 7300; d += 256){
    int row = d / 100, e = d - row * 100;
    int gr = r0 + row;
    float v = (gr >= 0 && gr < Ln) ? x[((size_t)b * Ln + gr) * 100 + e] : 0.f;
    x_s[e * 76 + row] = v;
  }
  __syncthreads();

  int f = tid & 63, lsub = tid >> 6;
  float acc[16];
#pragma unroll
  for (int j = 0; j < 16; j++) acc[j] = 0.f;

  for (int e = 0; e < 100; e++){
    float xv[25];
    const float* xr = x_s + e * 76 + lsub * 16;
#pragma unroll
    for (int i = 0; i < 6; i++){
      f32x4 q = *(const f32x4*)(xr + 4 * i);
      xv[4*i+0] = q[0]; xv[4*i+1] = q[1]; xv[4*i+2] = q[2]; xv[4*i+3] = q[3];
    }
    xv[24] = xr[24];
#pragma unroll
    for (int k = 0; k < KS; k++){
      float wv = WT[(e * 10 + k) * 64 + f];
#pragma unroll
      for (int j = 0; j < 16; j++) acc[j] += wv * xv[j + k];
    }
  }

  float bias = (f < FM) ? conv_b[f] : 0.f;
  size_t tbS = (size_t)(b * NT + t) * TILE_SHORTS;
#pragma unroll
  for (int j = 0; j < 16; j++){
    int l = lsub * 16 + j;
    int lgl = 64 * t + l;
    float hv = (lgl < LP && f < FM) ? tanhf(acc[j] + bias) : 0.f;
    short hb = f2bf(hv);
    // hA image: [fgrp(4)][l(64)][20]  (cols 16..19 are unread holes)
    Hp[tbS + (size_t)(f >> 4) * 1280 + (size_t)l * 20 + (f & 15)] = hb;
    h_t[l * 69 + f] = hb;
  }
  __syncthreads();
  int lane = tid & 63, wave = tid >> 6;
#pragma unroll
  for (int i = 0; i < 16; i++){
    int fo = wave + 4 * i;
    // hT image: [f(64)][72]  (cols 64..71 unread holes)
    Hp[tbS + HT_OFF + (size_t)fo * 72 + lane] = h_t[lane * 69 + fo];
  }
}

// ---------------- shared fragment helpers ----------------
__device__ __forceinline__ void scores_tile(const short* __restrict__ h_s,
                                            const S8 bu[2], int c, int g, f32x4 d[4])
{
#pragma unroll
  for (int ms = 0; ms < 4; ms++){
    f32x4 acc = {0.f, 0.f, 0.f, 0.f};
#pragma unroll
    for (int kf = 0; kf < 2; kf++){
      const short* pa = h_s + (2 * kf) * 1280 + (c + 16 * ms) * 20 + 4 * g;
      S8 a;
      a.l2[0] = *(const long*)pa;
      a.l2[1] = *(const long*)(pa + 1280);
      acc = __builtin_amdgcn_mfma_f32_16x16x32_bf16(a.v, bu[kf].v, acc, 0, 0, 0);
    }
    d[ms] = acc;
  }
}

__device__ __forceinline__ void load_bu(const float* __restrict__ U_w,
                                        int ywave, int c, int g, S8 bu[2]){
  int yv = ywave + c;
#pragma unroll
  for (int kf = 0; kf < 2; kf++)
#pragma unroll
    for (int i = 0; i < 8; i++){
      int fidx = 4 * g + (i & 3) + 16 * (i >> 2) + 32 * kf;
      float v = (yv < Yn && fidx < FM) ? U_w[yv * FM + fidx] : 0.f;
      bu[kf].s[i] = f2bf(v);
    }
}

// ---------------- K2 fused: pass1 Sexp -> invS (regs) ; pass2 alpha + m + logits -------
__global__ __launch_bounds__(512, 4) void k2_fused(
    const short* __restrict__ Hp,
    const float* __restrict__ U_w, const float* __restrict__ final_w,
    const float* __restrict__ final_b,
    float* __restrict__ logits, float* __restrict__ alpha_out,
    float* __restrict__ dump)
{
  int id = blockIdx.x;
  int xcd = id & 7, rr = id >> 3;           // rr in [0,140)
  int b   = xcd + ((rr >= NYB) ? 8 : 0);
  int y0  = ((rr >= NYB) ? rr - NYB : rr) * YB;

  int tid = threadIdx.x;
  int lane = tid & 63, wave = tid >> 6;     // wave 0..7
  int c = lane & 15, g = lane >> 4;
  int ywave = y0 + wave * 16;

  __shared__ __align__(16) short buf[2][TILE_SHORTS];
  __shared__ float awf[NW * 1024];          // per-wave [16 rows][64]: carry<=31 + 32 new

  S8 bu[2];
  load_bu(U_w, ywave, c, g, bu);

  const char* blob = (const char*)Hp + (size_t)b * NT * TILE_BYTES;

  // ======== pass 1: S = sum_l exp(score)  (R5 k2a loop, hA-only staging) ========
  float S = 0.f;
  {
    int cur = 0;
    stage_chunks(blob, (char*)buf[0], wave, lane, CH_A, NW);
    for (int t = 0; t < NT; t++){
      __syncthreads();
      if (t + 1 < NT)
        stage_chunks(blob + (size_t)(t + 1) * TILE_BYTES, (char*)buf[cur ^ 1], wave, lane, CH_A, NW);
      f32x4 d[4];
      scores_tile(buf[cur], bu, c, g, d);
      if (t < NT - 1){
#pragma unroll
        for (int ms = 0; ms < 4; ms++)
#pragma unroll
          for (int q = 0; q < 4; q++) S += __expf(d[ms][q]);
      } else {
#pragma unroll
        for (int ms = 0; ms < 4; ms++)
#pragma unroll
          for (int q = 0; q < 4; q++){
            int l = 64 * t + 16 * ms + 4 * g + q;
            if (l < LP) S += __expf(d[ms][q]);
          }
      }
      cur ^= 1;
    }
  }
  S += __shfl_xor(S, 16);
  S += __shfl_xor(S, 32);
  float invS = 1.f / S;                     // lane's y = ywave + c (C-layout col)
  __syncthreads();

  // ======== pass 2: alpha (pipelined full-line writes) + m  (R5 k2b loop) ========
  // alpha row phase: float index of (y,0) is 142737 + (b*8921+y)*2501 ; mod 32:
  int Kf = (17 + 29 * b + 5 * ywave) & 31;
  int fc = (Kf + 5 * c) & 31;

  f32x4 m2[4];
#pragma unroll
  for (int fs = 0; fs < 4; fs++) m2[fs] = (f32x4){0.f, 0.f, 0.f, 0.f};

  float* aw = awf + wave * 1024;
  float* dumpf = dump + (size_t)id * 64;

  int cur = 0;
  stage_chunks(blob, (char*)buf[0], wave, lane, CH_FULL, NW);
  for (int t = 0; t < NT; t++){
    if (t == 0) asm volatile("s_waitcnt vmcnt(0) lgkmcnt(0)" ::: "memory");
    else        asm volatile("s_waitcnt vmcnt(16) lgkmcnt(0)" ::: "memory");
    __builtin_amdgcn_s_barrier();
    if (t + 1 < NT)
      stage_chunks(blob + (size_t)(t + 1) * TILE_BYTES, (char*)buf[cur ^ 1], wave, lane, CH_FULL, NW);
    __builtin_amdgcn_sched_barrier(0);      // pin: loads issued before everything below

    const short* h_s  = buf[cur];
    const short* ht_s = buf[cur] + HT_OFF;
    f32x4 d[4];
    scores_tile(h_s, bu, c, g, d);
    float a[16];
    if (t < NT - 1){
#pragma unroll
      for (int ms = 0; ms < 4; ms++)
#pragma unroll
        for (int q = 0; q < 4; q++) a[ms * 4 + q] = __expf(d[ms][q]) * invS;
    } else {
#pragma unroll
      for (int ms = 0; ms < 4; ms++)
#pragma unroll
        for (int q = 0; q < 4; q++){
          int l = 64 * t + 16 * ms + 4 * g + q;
          a[ms * 4 + q] = (l < LP) ? __expf(d[ms][q]) * invS : 0.f;
        }
    }

    // GEMM2: m += alpha * h   (A2 repacked in-lane from scores^T fragments)
#pragma unroll
    for (int kl = 0; kl < 2; kl++){
      S8 a2;
#pragma unroll
      for (int i = 0; i < 8; i++)
        a2.s[i] = f2bf(a[(2 * kl + (i >> 2)) * 4 + (i & 3)]);
#pragma unroll
      for (int fs = 0; fs < 4; fs++){
        const short* pb = ht_s + (16 * fs + c) * 72 + 4 * g + 32 * kl;
        S8 b2;
        b2.l2[0] = *(const long*)pb;
        b2.l2[1] = *(const long*)(pb + 16);
        m2[fs] = __builtin_amdgcn_mfma_f32_16x16x32_bf16(a2.v, b2.v, m2[fs], 0, 0, 0);
      }
    }

    // alpha out: two half-rounds of 32 cols; every store is a full 128B line,
    // unconditional (OOB lanes redirected to dump) -> exactly 16 stores/wave/tile
#pragma unroll
    for (int hs = 0; hs < 2; hs++){
      // scatter 32 new alphas at row phase fc -> positions [fc, fc+32) (<=63)
#pragma unroll
      for (int mh = 0; mh < 2; mh++)
#pragma unroll
        for (int q = 0; q < 4; q++)
          aw[c * 64 + fc + 16 * mh + 4 * g + q] = a[(2 * hs + mh) * 4 + q];
      // store cols [0,32) of each row: 8 wave-stores (2 rows each)
#pragma unroll
      for (int i = 0; i < 8; i++){
        int jj  = 2 * i + (lane >> 5);
        int k32 = lane & 31;
        int fj  = (Kf + 5 * jj) & 31;
        int gcol = 64 * t + 32 * hs - fj + k32;
        float v = aw[jj * 64 + k32];
        int yj = ywave + jj;
        bool ok = (gcol >= 0) & (gcol < LP) & (yj < Yn);
        float* dst = ok ? (alpha_out + (size_t)(b * Yn + yj) * LP + gcol)
                        : (dumpf + lane);
        __builtin_nontemporal_store(v, dst);
      }
      // shift carry [32, 32+fj) -> [0, fj)
#pragma unroll
      for (int i = 0; i < 8; i++){
        int jj  = 2 * i + (lane >> 5);
        int k32 = lane & 31;
        int fj  = (Kf + 5 * jj) & 31;
        if (k32 < fj) aw[jj * 64 + k32] = aw[jj * 64 + 32 + k32];
      }
    }
    cur ^= 1;
  }

  // ---- epilogue: logits ----
  float part[4];
#pragma unroll
  for (int q = 0; q < 4; q++){
    int yy = ywave + 4 * g + q;
    float p = 0.f;
    if (yy < Yn){
#pragma unroll
      for (int fs = 0; fs < 4; fs++){
        int fcol = fs * 16 + c;
        if (fcol < FM) p += m2[fs][q] * final_w[yy * FM + fcol];
      }
    }
#pragma unroll
    for (int off = 1; off <= 8; off <<= 1) p += __shfl_xor(p, off);
    part[q] = p;
  }
  if (c == 0){
#pragma unroll
    for (int q = 0; q < 4; q++){
      int yy = ywave + 4 * g + q;
      if (yy < Yn) logits[(size_t)b * Yn + yy] = part[q] + final_b[yy];
    }
  }
}

// ---------------- K3: log_softmax over Y + BCE loss partials ----------------
__global__ __launch_bounds__(256) void k3_lsm(
    const float* __restrict__ logits, const float* __restrict__ target,
    float* __restrict__ proba, float* __restrict__ lossp)
{
  int b = blockIdx.x, tid = threadIdx.x;
  int lane = tid & 63, wave = tid >> 6;
  __shared__ float red[4];
  const float* lg = logits + (size_t)b * Yn;
  const float* tg = target + (size_t)b * Yn;

  float m = -INFINITY;
  for (int y = tid; y < Yn; y += 256) m = fmaxf(m, lg[y]);
#pragma unroll
  for (int off = 1; off <= 32; off <<= 1) m = fmaxf(m, __shfl_xor(m, off));
  if (lane == 0) red[wave] = m;
  __syncthreads();
  m = fmaxf(fmaxf(red[0], red[1]), fmaxf(red[2], red[3]));
  __syncthreads();

  float s = 0.f;
  for (int y = tid; y < Yn; y += 256) s += __expf(lg[y] - m);
#pragma unroll
  for (int off = 1; off <= 32; off <<= 1) s += __shfl_xor(s, off);
  if (lane == 0) red[wave] = s;
  __syncthreads();
  s = red[0] + red[1] + red[2] + red[3];
  __syncthreads();
  float lse = m + logf(s);

  float ls = 0.f;
  for (int y = tid; y < Yn; y += 256){
    float xx = lg[y];
    proba[(size_t)b * Yn + y] = xx - lse;
    ls += fmaxf(xx, 0.f) - xx * tg[y] + log1pf(__expf(-fabsf(xx)));
  }
#pragma unroll
  for (int off = 1; off <= 32; off <<= 1) ls += __shfl_xor(ls, off);
  if (lane == 0) red[wave] = ls;
  __syncthreads();
  if (tid == 0) lossp[b] = red[0] + red[1] + red[2] + red[3];
}

__global__ void k4_loss(const float* __restrict__ lossp, float* __restrict__ out){
  if (threadIdx.x == 0){
    float s = 0.f;
    for (int i = 0; i < Bn; i++) s += lossp[i];
    out[142736] = s / 142736.f;
  }
}

// ---------------- launch ----------------
extern "C" void kernel_launch(void* const* d_in, const int* in_sizes, int n_in,
                              void* d_out, int out_size, void* d_ws, size_t ws_size,
                              hipStream_t stream)
{
  const float* x       = (const float*)d_in[0];
  const float* target  = (const float*)d_in[1];
  const float* conv_w  = (const float*)d_in[2];
  const float* conv_b  = (const float*)d_in[3];
  const float* U_w     = (const float*)d_in[4];
  const float* final_w = (const float*)d_in[5];
  const float* final_b = (const float*)d_in[6];
  float* out = (float*)d_out;

  char* ws = (char*)d_ws;
  short* Hp     = (short*)(ws);                 // 16*40*19456 = 12,451,840 B
  float* WT     = (float*)(ws + 12451840);      //   256,000 B
  float* logits = (float*)(ws + 12707840);      //   570,944 B
  float* lossp  = (float*)(ws + 13278784);      //        64 B
  float* dump   = (float*)(ws + 13278848);      //   286,720 B  (1120 blocks * 256B)

  float* proba     = out;              // B*Y
  float* alpha_out = out + 142737;     // after proba + loss

  k0_wt<<<dim3(250), dim3(256), 0, stream>>>(conv_w, WT);
  k1_conv<<<dim3(8 * 2 * NT), dim3(256), 0, stream>>>(x, WT, conv_b, Hp);
  k2_fused<<<dim3(8 * 2 * NYB), dim3(512), 0, stream>>>(Hp, U_w, final_w, final_b,
                                                        logits, alpha_out, dump);
  k3_lsm<<<dim3(Bn), dim3(256), 0, stream>>>(logits, target, proba, lossp);
  k4_loss<<<dim3(1), dim3(64), 0, stream>>>(lossp, out);
}

// Round 9
// 596.169 us; speedup vs baseline: 1.2406x; 1.0078x over previous
//
#include <hip/hip_runtime.h>
#include <math.h>

#define Bn 16
#define Ln 2500
#define En 100
#define FM 50
#define Yn 8921
#define KS 10
#define LP 2501
#define NT 40              // 40 tiles of 64 l (2560 >= 2501)
#define TILE_BYTES 19456   // hA 10240 + hT 9216
#define TILE_SHORTS 9728
#define HT_OFF 5120        // shorts
#define CH_FULL 19         // 1KB chunks per full tile
#define CH_A 10            // chunks covering hA only
#define NW 8               // waves per K2 block
#define YB 128             // y per K2 block
#define NYB 70             // ceil(8921/128)

typedef __attribute__((ext_vector_type(8))) short short8;
typedef __attribute__((ext_vector_type(4))) float f32x4;

union S8 { short8 v; long l2[2]; short s[8]; };

__device__ __forceinline__ short f2bf(float f){
  unsigned u = __float_as_uint(f);
  unsigned r = (u + 0x7fffu + ((u >> 16) & 1u)) >> 16;
  return (short)r;
}

// async 16B/lane global->LDS
__device__ __forceinline__ void g2l16(const void* g, void* l){
  __builtin_amdgcn_global_load_lds(
      (const __attribute__((address_space(1))) unsigned int*)g,
      (__attribute__((address_space(3))) unsigned int*)l, 16, 0, 0);
}

__device__ __forceinline__ void stage_chunks(const char* __restrict__ gbase,
                                             char* lbase, int wave, int lane,
                                             int nch, int nw){
  for (int chunk = wave; chunk < nch; chunk += nw)
    g2l16(gbase + chunk * 1024 + lane * 16, lbase + chunk * 1024 + lane * 16);
}

// ---------------- K0: transpose conv_w (Fm,E,K) -> WT[e*10+k][f(64 pad0)] --------------
__global__ void k0_wt(const float* __restrict__ cw, float* __restrict__ WT){
  int i = blockIdx.x * 256 + threadIdx.x;
  if (i < 64000){
    int f = i & 63, ek = i >> 6;
    WT[i] = (f < FM) ? cw[f * 1000 + ek] : 0.f;
  }
}

// ---------------- K1: conv+bias+tanh -> per-tile blob [hA pad | hT pad] bf16 -----------
// 1D XCD-affine grid: tiles of batch b land on XCD b&7 (same as K2's reader mapping)
__global__ __launch_bounds__(256) void k1_conv(
    const float* __restrict__ x, const float* __restrict__ WT,
    const float* __restrict__ conv_b, short* __restrict__ Hp)
{
  int id = blockIdx.x;
  int xcd = id & 7, rr = id >> 3;           // rr in [0,80)
  int b   = xcd + ((rr >= NT) ? 8 : 0);
  int t   = (rr >= NT) ? rr - NT : rr;
  int tid = threadIdx.x;
  __shared__ float x_s[100 * 76];       // [e][row(73) pad 76]
  __shared__ short h_t[64 * 69];        // [l][f pad 69]

  int r0 = 64 * t - 5;
  for (int d = tid; d < 7300; d += 256){
    int row = d / 100, e = d - row * 100;
    int gr = r0 + row;
    float v = (gr >= 0 && gr < Ln) ? x[((size_t)b * Ln + gr) * 100 + e] : 0.f;
    x_s[e * 76 + row] = v;
  }
  __syncthreads();

  int f = tid & 63, lsub = tid >> 6;
  float acc[16];
#pragma unroll
  for (int j = 0; j < 16; j++) acc[j] = 0.f;

  for (int e = 0; e < 100; e++){
    float xv[25];
    const float* xr = x_s + e * 76 + lsub * 16;
#pragma unroll
    for (int i = 0; i < 6; i++){
      f32x4 q = *(const f32x4*)(xr + 4 * i);
      xv[4*i+0] = q[0]; xv[4*i+1] = q[1]; xv[4*i+2] = q[2]; xv[4*i+3] = q[3];
    }
    xv[24] = xr[24];
#pragma unroll
    for (int k = 0; k < KS; k++){
      float wv = WT[(e * 10 + k) * 64 + f];
#pragma unroll
      for (int j = 0; j < 16; j++) acc[j] += wv * xv[j + k];
    }
  }

  float bias = (f < FM) ? conv_b[f] : 0.f;
  size_t tbS = (size_t)(b * NT + t) * TILE_SHORTS;
#pragma unroll
  for (int j = 0; j < 16; j++){
    int l = lsub * 16 + j;
    int lgl = 64 * t + l;
    float hv = (lgl < LP && f < FM) ? tanhf(acc[j] + bias) : 0.f;
    short hb = f2bf(hv);
    // hA image: [fgrp(4)][l(64)][20]  (cols 16..19 are unread holes)
    Hp[tbS + (size_t)(f >> 4) * 1280 + (size_t)l * 20 + (f & 15)] = hb;
    h_t[l * 69 + f] = hb;
  }
  __syncthreads();
  int lane = tid & 63, wave = tid >> 6;
#pragma unroll
  for (int i = 0; i < 16; i++){
    int fo = wave + 4 * i;
    // hT image: [f(64)][72]  (cols 64..71 unread holes)
    Hp[tbS + HT_OFF + (size_t)fo * 72 + lane] = h_t[lane * 69 + fo];
  }
}

// ---------------- shared fragment helpers ----------------
__device__ __forceinline__ void scores_tile(const short* __restrict__ h_s,
                                            const S8 bu[2], int c, int g, f32x4 d[4])
{
#pragma unroll
  for (int ms = 0; ms < 4; ms++){
    f32x4 acc = {0.f, 0.f, 0.f, 0.f};
#pragma unroll
    for (int kf = 0; kf < 2; kf++){
      const short* pa = h_s + (2 * kf) * 1280 + (c + 16 * ms) * 20 + 4 * g;
      S8 a;
      a.l2[0] = *(const long*)pa;
      a.l2[1] = *(const long*)(pa + 1280);
      acc = __builtin_amdgcn_mfma_f32_16x16x32_bf16(a.v, bu[kf].v, acc, 0, 0, 0);
    }
    d[ms] = acc;
  }
}

__device__ __forceinline__ void load_bu(const float* __restrict__ U_w,
                                        int ywave, int c, int g, S8 bu[2]){
  int yv = ywave + c;
#pragma unroll
  for (int kf = 0; kf < 2; kf++)
#pragma unroll
    for (int i = 0; i < 8; i++){
      int fidx = 4 * g + (i & 3) + 16 * (i >> 2) + 32 * kf;
      float v = (yv < Yn && fidx < FM) ? U_w[yv * FM + fidx] : 0.f;
      bu[kf].s[i] = f2bf(v);
    }
}

// ---------------- K2 fused: pass1 Sexp -> invS (regs) ; pass2 alpha + m + logits -------
__global__ __launch_bounds__(512, 4) void k2_fused(
    const short* __restrict__ Hp,
    const float* __restrict__ U_w, const float* __restrict__ final_w,
    const float* __restrict__ final_b,
    float* __restrict__ logits, float* __restrict__ alpha_out,
    float* __restrict__ dump)
{
  int id = blockIdx.x;
  int xcd = id & 7, rr = id >> 3;           // rr in [0,140)
  int b   = xcd + ((rr >= NYB) ? 8 : 0);
  int y0  = ((rr >= NYB) ? rr - NYB : rr) * YB;

  int tid = threadIdx.x;
  int lane = tid & 63, wave = tid >> 6;     // wave 0..7
  int c = lane & 15, g = lane >> 4;
  int ywave = y0 + wave * 16;

  __shared__ __align__(16) short buf[2][TILE_SHORTS];
  __shared__ __align__(16) float awf[NW * 1024];  // per-wave [16 rows][64]

  S8 bu[2];
  load_bu(U_w, ywave, c, g, bu);

  const char* blob = (const char*)Hp + (size_t)b * NT * TILE_BYTES;

  // ======== pass 1: S = sum_l exp(score)  (hA-only staging) ========
  float S = 0.f;
  {
    int cur = 0;
    stage_chunks(blob, (char*)buf[0], wave, lane, CH_A, NW);
    for (int t = 0; t < NT; t++){
      __syncthreads();
      if (t + 1 < NT)
        stage_chunks(blob + (size_t)(t + 1) * TILE_BYTES, (char*)buf[cur ^ 1], wave, lane, CH_A, NW);
      f32x4 d[4];
      scores_tile(buf[cur], bu, c, g, d);
      if (t < NT - 1){
#pragma unroll
        for (int ms = 0; ms < 4; ms++)
#pragma unroll
          for (int q = 0; q < 4; q++) S += __expf(d[ms][q]);
      } else {
#pragma unroll
        for (int ms = 0; ms < 4; ms++)
#pragma unroll
          for (int q = 0; q < 4; q++){
            int l = 64 * t + 16 * ms + 4 * g + q;
            if (l < LP) S += __expf(d[ms][q]);
          }
      }
      cur ^= 1;
    }
  }
  S += __shfl_xor(S, 16);
  S += __shfl_xor(S, 32);
  float invS = 1.f / S;                     // lane's y = ywave + c (C-layout col)
  __syncthreads();

  // ======== pass 2: alpha (wide pipelined full-line writes) + m ========
  // alpha row phase: float index of (y,0) is 142737 + (b*8921+y)*2501 ; mod 32:
  int Kf = (17 + 29 * b + 5 * ywave) & 31;
  int fc = (Kf + 5 * c) & 31;

  f32x4 m2[4];
#pragma unroll
  for (int fs = 0; fs < 4; fs++) m2[fs] = (f32x4){0.f, 0.f, 0.f, 0.f};

  float* aw = awf + wave * 1024;
  float* dumpf = dump + (size_t)id * 256;   // 1KB per block

  int cur = 0;
  stage_chunks(blob, (char*)buf[0], wave, lane, CH_FULL, NW);
  for (int t = 0; t < NT; t++){
    // vmcnt ledger: newest outstanding at top of tile t = S(t-1):
    //   t=0: prologue loads only -> vmcnt(0)
    //   t=1: S(0)=16 (boundary path) -> vmcnt(16) retires L(1)
    //   t>=2: S(t-1)=4 (wide path; t-1 in [1,38]) -> vmcnt(4) retires L(t)+S(t-2)
    if (t == 0)      asm volatile("s_waitcnt vmcnt(0) lgkmcnt(0)" ::: "memory");
    else if (t == 1) asm volatile("s_waitcnt vmcnt(16) lgkmcnt(0)" ::: "memory");
    else             asm volatile("s_waitcnt vmcnt(4) lgkmcnt(0)" ::: "memory");
    __builtin_amdgcn_s_barrier();
    if (t + 1 < NT)
      stage_chunks(blob + (size_t)(t + 1) * TILE_BYTES, (char*)buf[cur ^ 1], wave, lane, CH_FULL, NW);
    __builtin_amdgcn_sched_barrier(0);      // pin: loads issued before everything below

    const short* h_s  = buf[cur];
    const short* ht_s = buf[cur] + HT_OFF;
    f32x4 d[4];
    scores_tile(h_s, bu, c, g, d);
    float a[16];
    if (t < NT - 1){
#pragma unroll
      for (int ms = 0; ms < 4; ms++)
#pragma unroll
        for (int q = 0; q < 4; q++) a[ms * 4 + q] = __expf(d[ms][q]) * invS;
    } else {
#pragma unroll
      for (int ms = 0; ms < 4; ms++)
#pragma unroll
        for (int q = 0; q < 4; q++){
          int l = 64 * t + 16 * ms + 4 * g + q;
          a[ms * 4 + q] = (l < LP) ? __expf(d[ms][q]) * invS : 0.f;
        }
    }

    // GEMM2: m += alpha * h   (A2 repacked in-lane from scores^T fragments)
#pragma unroll
    for (int kl = 0; kl < 2; kl++){
      S8 a2;
#pragma unroll
      for (int i = 0; i < 8; i++)
        a2.s[i] = f2bf(a[(2 * kl + (i >> 2)) * 4 + (i & 3)]);
#pragma unroll
      for (int fs = 0; fs < 4; fs++){
        const short* pb = ht_s + (16 * fs + c) * 72 + 4 * g + 32 * kl;
        S8 b2;
        b2.l2[0] = *(const long*)pb;
        b2.l2[1] = *(const long*)(pb + 16);
        m2[fs] = __builtin_amdgcn_mfma_f32_16x16x32_bf16(a2.v, b2.v, m2[fs], 0, 0, 0);
      }
    }

    // alpha out: two half-rounds of 32 cols; every store covers full aligned lines
#pragma unroll
    for (int hs = 0; hs < 2; hs++){
      // scatter 32 new alphas at row phase fc -> positions [fc, fc+32) (<=63)
#pragma unroll
      for (int mh = 0; mh < 2; mh++)
#pragma unroll
        for (int q = 0; q < 4; q++)
          aw[c * 64 + fc + 16 * mh + 4 * g + q] = a[(2 * hs + mh) * 4 + q];
      if (t >= 1 && t <= 38){
        // wide path: 2 dwordx4 stores/wave/half-round (8 lanes/row, 8 rows/instr)
        // alignment proven: global float idx === k4 (mod 32), k4 % 4 == 0 -> 16B
        // cols in [33,2498] -> only y mask needed
#pragma unroll
        for (int i = 0; i < 2; i++){
          int jj = 8 * i + (lane >> 3);
          int k4 = (lane & 7) * 4;
          int fj = (Kf + 5 * jj) & 31;
          int gcol = 64 * t + 32 * hs - fj + k4;
          f32x4 v4 = *(const f32x4*)(aw + jj * 64 + k4);
          int yj = ywave + jj;
          bool ok = (yj < Yn);
          f32x4* dst = ok ? (f32x4*)(alpha_out + (size_t)(b * Yn + yj) * LP + gcol)
                          : (f32x4*)(dumpf + 4 * lane);
          __builtin_nontemporal_store(v4, dst);
        }
      } else {
        // boundary path: 8 masked dword stores/wave (2 rows each)
#pragma unroll
        for (int i = 0; i < 8; i++){
          int jj  = 2 * i + (lane >> 5);
          int k32 = lane & 31;
          int fj  = (Kf + 5 * jj) & 31;
          int gcol = 64 * t + 32 * hs - fj + k32;
          float v = aw[jj * 64 + k32];
          int yj = ywave + jj;
          bool ok = (gcol >= 0) & (gcol < LP) & (yj < Yn);
          float* dst = ok ? (alpha_out + (size_t)(b * Yn + yj) * LP + gcol)
                          : (dumpf + lane);
          __builtin_nontemporal_store(v, dst);
        }
      }
      // shift carry [32, 32+fj) -> [0, fj)
#pragma unroll
      for (int i = 0; i < 8; i++){
        int jj  = 2 * i + (lane >> 5);
        int k32 = lane & 31;
        int fj  = (Kf + 5 * jj) & 31;
        if (k32 < fj) aw[jj * 64 + k32] = aw[jj * 64 + 32 + k32];
      }
    }
    cur ^= 1;
  }

  // ---- epilogue: logits ----
  float part[4];
#pragma unroll
  for (int q = 0; q < 4; q++){
    int yy = ywave + 4 * g + q;
    float p = 0.f;
    if (yy < Yn){
#pragma unroll
      for (int fs = 0; fs < 4; fs++){
        int fcol = fs * 16 + c;
        if (fcol < FM) p += m2[fs][q] * final_w[yy * FM + fcol];
      }
    }
#pragma unroll
    for (int off = 1; off <= 8; off <<= 1) p += __shfl_xor(p, off);
    part[q] = p;
  }
  if (c == 0){
#pragma unroll
    for (int q = 0; q < 4; q++){
      int yy = ywave + 4 * g + q;
      if (yy < Yn) logits[(size_t)b * Yn + yy] = part[q] + final_b[yy];
    }
  }
}

// ---------------- K3: log_softmax over Y + BCE loss partials ----------------
__global__ __launch_bounds__(256) void k3_lsm(
    const float* __restrict__ logits, const float* __restrict__ target,
    float* __restrict__ proba, float* __restrict__ lossp)
{
  int b = blockIdx.x, tid = threadIdx.x;
  int lane = tid & 63, wave = tid >> 6;
  __shared__ float red[4];
  const float* lg = logits + (size_t)b * Yn;
  const float* tg = target + (size_t)b * Yn;

  float m = -INFINITY;
  for (int y = tid; y < Yn; y += 256) m = fmaxf(m, lg[y]);
#pragma unroll
  for (int off = 1; off <= 32; off <<= 1) m = fmaxf(m, __shfl_xor(m, off));
  if (lane == 0) red[wave] = m;
  __syncthreads();
  m = fmaxf(fmaxf(red[0], red[1]), fmaxf(red[2], red[3]));
  __syncthreads();

  float s = 0.f;
  for (int y = tid; y < Yn; y += 256) s += __expf(lg[y] - m);
#pragma unroll
  for (int off = 1; off <= 32; off <<= 1) s += __shfl_xor(s, off);
  if (lane == 0) red[wave] = s;
  __syncthreads();
  s = red[0] + red[1] + red[2] + red[3];
  __syncthreads();
  float lse = m + logf(s);

  float ls = 0.f;
  for (int y = tid; y < Yn; y += 256){
    float xx = lg[y];
    proba[(size_t)b * Yn + y] = xx - lse;
    ls += fmaxf(xx, 0.f) - xx * tg[y] + log1pf(__expf(-fabsf(xx)));
  }
#pragma unroll
  for (int off = 1; off <= 32; off <<= 1) ls += __shfl_xor(ls, off);
  if (lane == 0) red[wave] = ls;
  __syncthreads();
  if (tid == 0) lossp[b] = red[0] + red[1] + red[2] + red[3];
}

__global__ void k4_loss(const float* __restrict__ lossp, float* __restrict__ out){
  if (threadIdx.x == 0){
    float s = 0.f;
    for (int i = 0; i < Bn; i++) s += lossp[i];
    out[142736] = s / 142736.f;
  }
}

// ---------------- launch ----------------
extern "C" void kernel_launch(void* const* d_in, const int* in_sizes, int n_in,
                              void* d_out, int out_size, void* d_ws, size_t ws_size,
                              hipStream_t stream)
{
  const float* x       = (const float*)d_in[0];
  const float* target  = (const float*)d_in[1];
  const float* conv_w  = (const float*)d_in[2];
  const float* conv_b  = (const float*)d_in[3];
  const float* U_w     = (const float*)d_in[4];
  const float* final_w = (const float*)d_in[5];
  const float* final_b = (const float*)d_in[6];
  float* out = (float*)d_out;

  char* ws = (char*)d_ws;
  short* Hp     = (short*)(ws);                 // 16*40*19456 = 12,451,840 B
  float* WT     = (float*)(ws + 12451840);      //   256,000 B
  float* logits = (float*)(ws + 12707840);      //   570,944 B
  float* lossp  = (float*)(ws + 13278784);      //        64 B
  float* dump   = (float*)(ws + 13278848);      // 1,146,880 B  (1120 blocks * 1KB)

  float* proba     = out;              // B*Y
  float* alpha_out = out + 142737;     // after proba + loss

  k0_wt<<<dim3(250), dim3(256), 0, stream>>>(conv_w, WT);
  k1_conv<<<dim3(8 * 2 * NT), dim3(256), 0, stream>>>(x, WT, conv_b, Hp);
  k2_fused<<<dim3(8 * 2 * NYB), dim3(512), 0, stream>>>(Hp, U_w, final_w, final_b,
                                                        logits, alpha_out, dump);
  k3_lsm<<<dim3(Bn), dim3(256), 0, stream>>>(logits, target, proba, lossp);
  k4_loss<<<dim3(1), dim3(64), 0, stream>>>(lossp, out);
}

// Round 10
// 584.496 us; speedup vs baseline: 1.2654x; 1.0200x over previous
//
#include <hip/hip_runtime.h>
#include <math.h>

#define Bn 16
#define Ln 2500
#define En 100
#define FM 50
#define Yn 8921
#define KS 10
#define LP 2501
#define NT 40              // 40 tiles of 64 l (2560 >= 2501)
#define TILE_SHORTS 5120   // hA only: [4][64][20] bf16
#define TILE_BYTES 10240
#define CH 10              // 1KB chunks per tile
#define NW 8               // waves per K2 block
#define YB 128             // y per K2 block
#define NYB 70             // ceil(8921/128)

typedef __attribute__((ext_vector_type(8))) short short8;
typedef __attribute__((ext_vector_type(4))) float f32x4;

union S8 { short8 v; long l2[2]; short s[8]; };

__device__ __forceinline__ short f2bf(float f){
  unsigned u = __float_as_uint(f);
  unsigned r = (u + 0x7fffu + ((u >> 16) & 1u)) >> 16;
  return (short)r;
}

// async 16B/lane global->LDS
__device__ __forceinline__ void g2l16(const void* g, void* l){
  __builtin_amdgcn_global_load_lds(
      (const __attribute__((address_space(1))) unsigned int*)g,
      (__attribute__((address_space(3))) unsigned int*)l, 16, 0, 0);
}

__device__ __forceinline__ void stage_chunks(const char* __restrict__ gbase,
                                             char* lbase, int wave, int lane){
  for (int chunk = wave; chunk < CH; chunk += NW)
    g2l16(gbase + chunk * 1024 + lane * 16, lbase + chunk * 1024 + lane * 16);
}

// ---------------- K0: transpose conv_w (Fm,E,K) -> WT[e*10+k][f(64 pad0)] --------------
__global__ void k0_wt(const float* __restrict__ cw, float* __restrict__ WT){
  int i = blockIdx.x * 256 + threadIdx.x;
  if (i < 64000){
    int f = i & 63, ek = i >> 6;
    WT[i] = (f < FM) ? cw[f * 1000 + ek] : 0.f;
  }
}

// ---------------- K1: conv+bias+tanh -> per-tile blob (hA image only) bf16 -------------
// 1D XCD-affine grid: tiles of batch b land on XCD b&7 (same as K2's reader mapping)
__global__ __launch_bounds__(256) void k1_conv(
    const float* __restrict__ x, const float* __restrict__ WT,
    const float* __restrict__ conv_b, short* __restrict__ Hp)
{
  int id = blockIdx.x;
  int xcd = id & 7, rr = id >> 3;           // rr in [0,80)
  int b   = xcd + ((rr >= NT) ? 8 : 0);
  int t   = (rr >= NT) ? rr - NT : rr;
  int tid = threadIdx.x;
  __shared__ float x_s[100 * 76];       // [e][row(73) pad 76]

  int r0 = 64 * t - 5;
  for (int d = tid; d < 7300; d += 256){
    int row = d / 100, e = d - row * 100;
    int gr = r0 + row;
    float v = (gr >= 0 && gr < Ln) ? x[((size_t)b * Ln + gr) * 100 + e] : 0.f;
    x_s[e * 76 + row] = v;
  }
  __syncthreads();

  int f = tid & 63, lsub = tid >> 6;
  float acc[16];
#pragma unroll
  for (int j = 0; j < 16; j++) acc[j] = 0.f;

  for (int e = 0; e < 100; e++){
    float xv[25];
    const float* xr = x_s + e * 76 + lsub * 16;
#pragma unroll
    for (int i = 0; i < 6; i++){
      f32x4 q = *(const f32x4*)(xr + 4 * i);
      xv[4*i+0] = q[0]; xv[4*i+1] = q[1]; xv[4*i+2] = q[2]; xv[4*i+3] = q[3];
    }
    xv[24] = xr[24];
#pragma unroll
    for (int k = 0; k < KS; k++){
      float wv = WT[(e * 10 + k) * 64 + f];
#pragma unroll
      for (int j = 0; j < 16; j++) acc[j] += wv * xv[j + k];
    }
  }

  float bias = (f < FM) ? conv_b[f] : 0.f;
  size_t tbS = (size_t)(b * NT + t) * TILE_SHORTS;
#pragma unroll
  for (int j = 0; j < 16; j++){
    int l = lsub * 16 + j;
    int lgl = 64 * t + l;
    float hv = (lgl < LP && f < FM) ? tanhf(acc[j] + bias) : 0.f;
    // hA image: [fgrp(4)][l(64)][20]  (cols 16..19 are unread holes)
    Hp[tbS + (size_t)(f >> 4) * 1280 + (size_t)l * 20 + (f & 15)] = f2bf(hv);
  }
}

// ---------------- shared fragment helpers ----------------
__device__ __forceinline__ void scores_tile(const short* __restrict__ h_s,
                                            const S8 bu[2], int c, int g, f32x4 d[4])
{
#pragma unroll
  for (int ms = 0; ms < 4; ms++){
    f32x4 acc = {0.f, 0.f, 0.f, 0.f};
#pragma unroll
    for (int kf = 0; kf < 2; kf++){
      const short* pa = h_s + (2 * kf) * 1280 + (c + 16 * ms) * 20 + 4 * g;
      S8 a;
      a.l2[0] = *(const long*)pa;
      a.l2[1] = *(const long*)(pa + 1280);
      acc = __builtin_amdgcn_mfma_f32_16x16x32_bf16(a.v, bu[kf].v, acc, 0, 0, 0);
    }
    d[ms] = acc;
  }
}

__device__ __forceinline__ void load_bu(const float* __restrict__ U_w,
                                        int ywave, int c, int g, S8 bu[2]){
  int yv = ywave + c;
#pragma unroll
  for (int kf = 0; kf < 2; kf++)
#pragma unroll
    for (int i = 0; i < 8; i++){
      int fidx = 4 * g + (i & 3) + 16 * (i >> 2) + 32 * kf;
      float v = (yv < Yn && fidx < FM) ? U_w[yv * FM + fidx] : 0.f;
      bu[kf].s[i] = f2bf(v);
    }
}

// ---------------- K2 fused: pass1 Sexp -> invS (regs) ; pass2 alpha + m^T + logits -----
__global__ __launch_bounds__(512, 4) void k2_fused(
    const short* __restrict__ Hp,
    const float* __restrict__ U_w, const float* __restrict__ final_w,
    const float* __restrict__ final_b,
    float* __restrict__ logits, float* __restrict__ alpha_out,
    float* __restrict__ dump)
{
  int id = blockIdx.x;
  int xcd = id & 7, rr = id >> 3;           // rr in [0,140)
  int b   = xcd + ((rr >= NYB) ? 8 : 0);
  int y0  = ((rr >= NYB) ? rr - NYB : rr) * YB;

  int tid = threadIdx.x;
  int lane = tid & 63, wave = tid >> 6;     // wave 0..7
  int c = lane & 15, g = lane >> 4;
  int ywave = y0 + wave * 16;

  __shared__ __align__(16) short buf[2][TILE_SHORTS];
  __shared__ __align__(16) float awf[NW * 1024];  // per-wave [16 rows][64]

  S8 bu[2];
  load_bu(U_w, ywave, c, g, bu);

  const char* blob = (const char*)Hp + (size_t)b * NT * TILE_BYTES;

  // ======== pass 1: S = sum_l exp(score) ========
  float S = 0.f;
  {
    int cur = 0;
    stage_chunks(blob, (char*)buf[0], wave, lane);
    for (int t = 0; t < NT; t++){
      __syncthreads();
      if (t + 1 < NT)
        stage_chunks(blob + (size_t)(t + 1) * TILE_BYTES, (char*)buf[cur ^ 1], wave, lane);
      f32x4 d[4];
      scores_tile(buf[cur], bu, c, g, d);
      if (t < NT - 1){
#pragma unroll
        for (int ms = 0; ms < 4; ms++)
#pragma unroll
          for (int q = 0; q < 4; q++) S += __expf(d[ms][q]);
      } else {
#pragma unroll
        for (int ms = 0; ms < 4; ms++)
#pragma unroll
          for (int q = 0; q < 4; q++){
            int l = 64 * t + 16 * ms + 4 * g + q;
            if (l < LP) S += __expf(d[ms][q]);
          }
      }
      cur ^= 1;
    }
  }
  S += __shfl_xor(S, 16);
  S += __shfl_xor(S, 32);
  float invS = 1.f / S;                     // lane's y = ywave + c
  __syncthreads();

  // ======== pass 2: alpha (wide pipelined full-line writes) + m^T ========
  // alpha row phase: float index of (y,0) is 142737 + (b*8921+y)*2501 ; mod 32:
  int Kf = (17 + 29 * b + 5 * ywave) & 31;
  int fc = (Kf + 5 * c) & 31;

  f32x4 m2[4];                              // m2[fs][q] = m[y=ywave+c][f=16fs+4g+q]
#pragma unroll
  for (int fs = 0; fs < 4; fs++) m2[fs] = (f32x4){0.f, 0.f, 0.f, 0.f};

  float* aw = awf + wave * 1024;
  float* dumpf = dump + (size_t)id * 256;   // 1KB per block

  int cur = 0;
  stage_chunks(blob, (char*)buf[0], wave, lane);
  for (int t = 0; t < NT; t++){
    // vmcnt ledger: issue order in tile t-1 = [L(t) loads, S(t-1) stores];
    //   t=0: vmcnt(0); t=1: S(0)=16 (boundary) -> vmcnt(16); t>=2: S(t-1)=4 -> vmcnt(4)
    if (t == 0)      asm volatile("s_waitcnt vmcnt(0) lgkmcnt(0)" ::: "memory");
    else if (t == 1) asm volatile("s_waitcnt vmcnt(16) lgkmcnt(0)" ::: "memory");
    else             asm volatile("s_waitcnt vmcnt(4) lgkmcnt(0)" ::: "memory");
    __builtin_amdgcn_s_barrier();
    if (t + 1 < NT)
      stage_chunks(blob + (size_t)(t + 1) * TILE_BYTES, (char*)buf[cur ^ 1], wave, lane);
    __builtin_amdgcn_sched_barrier(0);      // pin: loads issued before everything below

    const short* h_s = buf[cur];
    f32x4 d[4];
    scores_tile(h_s, bu, c, g, d);
    float a[16];
    if (t < NT - 1){
#pragma unroll
      for (int ms = 0; ms < 4; ms++)
#pragma unroll
        for (int q = 0; q < 4; q++) a[ms * 4 + q] = __expf(d[ms][q]) * invS;
    } else {
#pragma unroll
      for (int ms = 0; ms < 4; ms++)
#pragma unroll
        for (int q = 0; q < 4; q++){
          int l = 64 * t + 16 * ms + 4 * g + q;
          a[ms * 4 + q] = (l < LP) ? __expf(d[ms][q]) * invS : 0.f;
        }
    }

    // GEMM2 (swapped): m^T += h^T * alpha^T
    //   A = h fragment: A[m=f_local=c (+16fs)][k=l], 8 ds_read_u16 from hA image
    //   B = alpha fragment: same in-lane repack bytes as before (k-slots match)
#pragma unroll
    for (int kl = 0; kl < 2; kl++){
      S8 a2;
#pragma unroll
      for (int i = 0; i < 8; i++)
        a2.s[i] = f2bf(a[(2 * kl + (i >> 2)) * 4 + (i & 3)]);
#pragma unroll
      for (int fs = 0; fs < 4; fs++){
        const short* pa2 = h_s + fs * 1280 + (4 * g + 32 * kl) * 20 + c;
        S8 av;
#pragma unroll
        for (int i = 0; i < 8; i++)
          av.s[i] = pa2[(i & 3) * 20 + (i >> 2) * 320];
        m2[fs] = __builtin_amdgcn_mfma_f32_16x16x32_bf16(av.v, a2.v, m2[fs], 0, 0, 0);
      }
    }

    // alpha out: two half-rounds of 32 cols; every store covers full aligned lines
#pragma unroll
    for (int hs = 0; hs < 2; hs++){
      // scatter 32 new alphas at row phase fc -> positions [fc, fc+32) (<=63)
#pragma unroll
      for (int mh = 0; mh < 2; mh++)
#pragma unroll
        for (int q = 0; q < 4; q++)
          aw[c * 64 + fc + 16 * mh + 4 * g + q] = a[(2 * hs + mh) * 4 + q];
      if (t >= 1 && t <= 38){
        // wide path: 2 dwordx4 stores/wave/half-round (8 lanes/row, 8 rows/instr)
#pragma unroll
        for (int i = 0; i < 2; i++){
          int jj = 8 * i + (lane >> 3);
          int k4 = (lane & 7) * 4;
          int fj = (Kf + 5 * jj) & 31;
          int gcol = 64 * t + 32 * hs - fj + k4;
          f32x4 v4 = *(const f32x4*)(aw + jj * 64 + k4);
          int yj = ywave + jj;
          bool ok = (yj < Yn);
          f32x4* dst = ok ? (f32x4*)(alpha_out + (size_t)(b * Yn + yj) * LP + gcol)
                          : (f32x4*)(dumpf + 4 * lane);
          __builtin_nontemporal_store(v4, dst);
        }
      } else {
        // boundary path: 8 masked dword stores/wave (2 rows each)
#pragma unroll
        for (int i = 0; i < 8; i++){
          int jj  = 2 * i + (lane >> 5);
          int k32 = lane & 31;
          int fj  = (Kf + 5 * jj) & 31;
          int gcol = 64 * t + 32 * hs - fj + k32;
          float v = aw[jj * 64 + k32];
          int yj = ywave + jj;
          bool ok = (gcol >= 0) & (gcol < LP) & (yj < Yn);
          float* dst = ok ? (alpha_out + (size_t)(b * Yn + yj) * LP + gcol)
                          : (dumpf + lane);
          __builtin_nontemporal_store(v, dst);
        }
      }
      // shift carry [32, 32+fj) -> [0, fj)
#pragma unroll
      for (int i = 0; i < 8; i++){
        int jj  = 2 * i + (lane >> 5);
        int k32 = lane & 31;
        int fj  = (Kf + 5 * jj) & 31;
        if (k32 < fj) aw[jj * 64 + k32] = aw[jj * 64 + 32 + k32];
      }
    }
    cur ^= 1;
  }

  // ---- epilogue: logits (m^T layout: lane holds y=ywave+c, f=16fs+4g+q) ----
  float p = 0.f;
  int yv = ywave + c;
  if (yv < Yn){
#pragma unroll
    for (int fs = 0; fs < 4; fs++)
#pragma unroll
      for (int q = 0; q < 4; q++){
        int fcol = 16 * fs + 4 * g + q;
        if (fcol < FM) p += m2[fs][q] * final_w[yv * FM + fcol];
      }
  }
  p += __shfl_xor(p, 16);
  p += __shfl_xor(p, 32);
  if (g == 0 && yv < Yn)
    logits[(size_t)b * Yn + yv] = p + final_b[yv];
}

// ---------------- K3: log_softmax over Y + BCE loss partials ----------------
__global__ __launch_bounds__(256) void k3_lsm(
    const float* __restrict__ logits, const float* __restrict__ target,
    float* __restrict__ proba, float* __restrict__ lossp)
{
  int b = blockIdx.x, tid = threadIdx.x;
  int lane = tid & 63, wave = tid >> 6;
  __shared__ float red[4];
  const float* lg = logits + (size_t)b * Yn;
  const float* tg = target + (size_t)b * Yn;

  float m = -INFINITY;
  for (int y = tid; y < Yn; y += 256) m = fmaxf(m, lg[y]);
#pragma unroll
  for (int off = 1; off <= 32; off <<= 1) m = fmaxf(m, __shfl_xor(m, off));
  if (lane == 0) red[wave] = m;
  __syncthreads();
  m = fmaxf(fmaxf(red[0], red[1]), fmaxf(red[2], red[3]));
  __syncthreads();

  float s = 0.f;
  for (int y = tid; y < Yn; y += 256) s += __expf(lg[y] - m);
#pragma unroll
  for (int off = 1; off <= 32; off <<= 1) s += __shfl_xor(s, off);
  if (lane == 0) red[wave] = s;
  __syncthreads();
  s = red[0] + red[1] + red[2] + red[3];
  __syncthreads();
  float lse = m + logf(s);

  float ls = 0.f;
  for (int y = tid; y < Yn; y += 256){
    float xx = lg[y];
    proba[(size_t)b * Yn + y] = xx - lse;
    ls += fmaxf(xx, 0.f) - xx * tg[y] + log1pf(__expf(-fabsf(xx)));
  }
#pragma unroll
  for (int off = 1; off <= 32; off <<= 1) ls += __shfl_xor(ls, off);
  if (lane == 0) red[wave] = ls;
  __syncthreads();
  if (tid == 0) lossp[b] = red[0] + red[1] + red[2] + red[3];
}

__global__ void k4_loss(const float* __restrict__ lossp, float* __restrict__ out){
  if (threadIdx.x == 0){
    float s = 0.f;
    for (int i = 0; i < Bn; i++) s += lossp[i];
    out[142736] = s / 142736.f;
  }
}

// ---------------- launch ----------------
extern "C" void kernel_launch(void* const* d_in, const int* in_sizes, int n_in,
                              void* d_out, int out_size, void* d_ws, size_t ws_size,
                              hipStream_t stream)
{
  const float* x       = (const float*)d_in[0];
  const float* target  = (const float*)d_in[1];
  const float* conv_w  = (const float*)d_in[2];
  const float* conv_b  = (const float*)d_in[3];
  const float* U_w     = (const float*)d_in[4];
  const float* final_w = (const float*)d_in[5];
  const float* final_b = (const float*)d_in[6];
  float* out = (float*)d_out;

  char* ws = (char*)d_ws;
  short* Hp     = (short*)(ws);                 // 16*40*10240 = 6,553,600 B
  float* WT     = (float*)(ws + 6553600);       //   256,000 B
  float* logits = (float*)(ws + 6809600);       //   570,944 B
  float* lossp  = (float*)(ws + 7380544);       //        64 B
  float* dump   = (float*)(ws + 7380608);       // 1,146,880 B  (1120 blocks * 1KB)

  float* proba     = out;              // B*Y
  float* alpha_out = out + 142737;     // after proba + loss

  k0_wt<<<dim3(250), dim3(256), 0, stream>>>(conv_w, WT);
  k1_conv<<<dim3(8 * 2 * NT), dim3(256), 0, stream>>>(x, WT, conv_b, Hp);
  k2_fused<<<dim3(8 * 2 * NYB), dim3(512), 0, stream>>>(Hp, U_w, final_w, final_b,
                                                        logits, alpha_out, dump);
  k3_lsm<<<dim3(Bn), dim3(256), 0, stream>>>(logits, target, proba, lossp);
  k4_loss<<<dim3(1), dim3(64), 0, stream>>>(lossp, out);
}